// Round 1
// baseline (312.450 us; speedup 1.0000x reference)
//
#include <hip/hip_runtime.h>
#include <cmath>

#define B_   2
#define C_   256
#define HC_  128
#define DC_  3
#define H_   48
#define W_   48
#define HW_  (H_ * W_)      // 2304
#define NP_  (B_ * HW_)     // 4608
#define K_   (DC_ * 49)     // 147

// ---------------------------------------------------------------------------
// 1) Fused psi/g projection: out[o] = sum_c w[o,c] * ctx[b,c,d,p]
//    psi layout: [B, 128, 3, HW]  (channel-major, coalesced for scores stage)
//    g   layout: [B, 3, HW, 128]  (channel-last, coalesced for PV stage)
// grid = (HW/32, B*DC), block = 256
// waves 0-1 of each block do psi (o 0..127), waves 2-3 do g (o 0..127)
__global__ __launch_bounds__(256) void proj_ctx_kernel(
    const float* __restrict__ psi_w, const float* __restrict__ g_w,
    const float* __restrict__ ctx, float* __restrict__ psiO, float* __restrict__ gO)
{
    int b = blockIdx.y / DC_, d = blockIdx.y % DC_;
    int tid = threadIdx.x;
    int og = tid >> 3;              // 0..31
    int pg = tid & 7;               // 0..7
    int p0 = blockIdx.x * 32 + pg * 4;
    bool isG = og >= 16;
    int o0 = (og & 15) * 8;
    const float* w = isG ? g_w : psi_w;
    const float* inb = ctx + (b * C_ * DC_ + d) * HW_;

    float acc[8][4];
    #pragma unroll
    for (int r = 0; r < 8; ++r)
        acc[r][0] = acc[r][1] = acc[r][2] = acc[r][3] = 0.f;

    for (int c = 0; c < C_; ++c) {
        float4 iv = *(const float4*)(inb + c * (DC_ * HW_) + p0);
        #pragma unroll
        for (int r = 0; r < 8; ++r) {
            float wv = w[(o0 + r) * C_ + c];
            acc[r][0] = fmaf(wv, iv.x, acc[r][0]);
            acc[r][1] = fmaf(wv, iv.y, acc[r][1]);
            acc[r][2] = fmaf(wv, iv.z, acc[r][2]);
            acc[r][3] = fmaf(wv, iv.w, acc[r][3]);
        }
    }

    if (!isG) {
        #pragma unroll
        for (int r = 0; r < 8; ++r) {
            float4 v = make_float4(acc[r][0], acc[r][1], acc[r][2], acc[r][3]);
            *(float4*)(psiO + ((b * HC_ + o0 + r) * DC_ + d) * HW_ + p0) = v;
        }
    } else {
        #pragma unroll
        for (int q2 = 0; q2 < 4; ++q2) {
            float* op = gO + ((b * DC_ + d) * HW_ + p0 + q2) * HC_ + o0;
            *(float4*)(op)     = make_float4(acc[0][q2], acc[1][q2], acc[2][q2], acc[3][q2]);
            *(float4*)(op + 4) = make_float4(acc[4][q2], acc[5][q2], acc[6][q2], acc[7][q2]);
        }
    }
}

// 2) q projection: q layout [B, HW, 128] (per-pixel contiguous over h)
// grid = (HW/64, B), block = 256
__global__ __launch_bounds__(256) void proj_q_kernel(
    const float* __restrict__ theta_w, const float* __restrict__ x,
    float* __restrict__ qO)
{
    int b = blockIdx.y;
    int tid = threadIdx.x;
    int og = tid >> 4;              // 0..15
    int pg = tid & 15;              // 0..15
    int p0 = blockIdx.x * 64 + pg * 4;
    int o0 = og * 8;
    const float* inb = x + b * C_ * HW_;

    float acc[8][4];
    #pragma unroll
    for (int r = 0; r < 8; ++r)
        acc[r][0] = acc[r][1] = acc[r][2] = acc[r][3] = 0.f;

    for (int c = 0; c < C_; ++c) {
        float4 iv = *(const float4*)(inb + c * HW_ + p0);
        #pragma unroll
        for (int r = 0; r < 8; ++r) {
            float wv = theta_w[(o0 + r) * C_ + c];
            acc[r][0] = fmaf(wv, iv.x, acc[r][0]);
            acc[r][1] = fmaf(wv, iv.y, acc[r][1]);
            acc[r][2] = fmaf(wv, iv.z, acc[r][2]);
            acc[r][3] = fmaf(wv, iv.w, acc[r][3]);
        }
    }
    #pragma unroll
    for (int q2 = 0; q2 < 4; ++q2) {
        float* op = qO + (b * HW_ + p0 + q2) * HC_ + o0;
        *(float4*)(op)     = make_float4(acc[0][q2], acc[1][q2], acc[2][q2], acc[3][q2]);
        *(float4*)(op + 4) = make_float4(acc[4][q2], acc[5][q2], acc[6][q2], acc[7][q2]);
    }
}

// 3) attention: one wave per pixel. Scores with lane=key, softmax via wave
//    shuffles, att transposed through LDS, PV with lane=channel.
// grid = NP/4, block = 256 (4 waves = 4 pixels)
__global__ __launch_bounds__(256) void attn_kernel(
    const float* __restrict__ q, const float* __restrict__ psi,
    const float* __restrict__ g, float* __restrict__ y)
{
    __shared__ float lds_att[4][192];
    int wv = threadIdx.x >> 6;
    int lane = threadIdx.x & 63;
    int gp = blockIdx.x * 4 + wv;       // global pixel, 0..4607 (b boundary aligns)
    int b = gp / HW_;
    int p = gp - b * HW_;
    int y0 = p / W_, x0 = p - y0 * W_;

    // per-lane key decomposition for the 3 chunks (k = chunk*64 + lane)
    int offs[3];
    #pragma unroll
    for (int c2 = 0; c2 < 3; ++c2) {
        int k = c2 * 64 + lane;
        int kk = k < K_ ? k : (K_ - 1);
        int dd = (kk >= 98) ? 2 : (kk >= 49 ? 1 : 0);
        int r = kk - dd * 49;
        int i = (r >= 7) + (r >= 14) + (r >= 21) + (r >= 28) + (r >= 35) + (r >= 42);
        int j = r - i * 7;
        int ny = min(max(y0 + i - 3, 0), H_ - 1);
        int nx = min(max(x0 + j - 3, 0), W_ - 1);
        offs[c2] = dd * HW_ + ny * W_ + nx;
    }

    const float* psiB = psi + b * (HC_ * DC_ * HW_);
    const float* qB = q + (b * HW_ + p) * HC_;

    float s0 = 0.f, s1 = 0.f, s2 = 0.f;
    for (int h = 0; h < HC_; h += 4) {
        float4 qv = *(const float4*)(qB + h);   // wave-uniform, L1 broadcast
        #pragma unroll
        for (int u = 0; u < 4; ++u) {
            const float* pp = psiB + (h + u) * (DC_ * HW_);
            float qh = (u == 0) ? qv.x : (u == 1) ? qv.y : (u == 2) ? qv.z : qv.w;
            s0 = fmaf(qh, pp[offs[0]], s0);
            s1 = fmaf(qh, pp[offs[1]], s1);
            s2 = fmaf(qh, pp[offs[2]], s2);
        }
    }
    if (lane + 128 >= K_) s2 = -INFINITY;   // only chunk 2 has invalid lanes

    float m = fmaxf(fmaxf(s0, s1), s2);
    #pragma unroll
    for (int off = 32; off; off >>= 1) m = fmaxf(m, __shfl_xor(m, off));
    float e0 = __expf(s0 - m), e1 = __expf(s1 - m), e2 = __expf(s2 - m);
    float sum = e0 + e1 + e2;
    #pragma unroll
    for (int off = 32; off; off >>= 1) sum += __shfl_xor(sum, off);
    float inv = 1.0f / sum;

    lds_att[wv][lane]       = e0 * inv;
    lds_att[wv][64 + lane]  = e1 * inv;
    lds_att[wv][128 + lane] = e2 * inv;   // invalid lanes wrote 0 (exp(-inf)=0)
    __syncthreads();

    // PV: lane = channel (h0 = lane, h1 = lane+64); g loads fully coalesced
    const float* gB = g + b * (DC_ * HW_ * HC_);
    float a0 = 0.f, a1 = 0.f;
    for (int dd = 0; dd < DC_; ++dd) {
        #pragma unroll
        for (int i = 0; i < 7; ++i) {
            int ny = min(max(y0 + i - 3, 0), H_ - 1);
            #pragma unroll
            for (int j = 0; j < 7; ++j) {
                int nx = min(max(x0 + j - 3, 0), W_ - 1);
                float a = lds_att[wv][(dd * 7 + i) * 7 + j];
                const float* gp2 = gB + (dd * HW_ + ny * W_ + nx) * HC_;
                a0 = fmaf(a, gp2[lane], a0);
                a1 = fmaf(a, gp2[64 + lane], a1);
            }
        }
    }
    float* yp = y + (b * HW_ + p) * HC_;
    yp[lane] = a0;
    yp[64 + lane] = a1;
}

// 4) wy = W_w @ y  (W_b skipped: a per-channel constant cancels exactly under
//    training-mode BN since wy - mean(wy) is invariant to it)
//    wy layout [B, 256, HW].  grid = NP/32, block = 256
__global__ __launch_bounds__(256) void wy_kernel(
    const float* __restrict__ Ww, const float* __restrict__ yIn,
    float* __restrict__ wyO)
{
    int tid = threadIdx.x;
    int og = tid >> 3;              // 0..31 -> o0 covers 256
    int pg = tid & 7;               // 0..7  -> 4 px each
    int gp0 = blockIdx.x * 32 + pg * 4;
    int o0 = og * 8;

    float acc[8][4];
    #pragma unroll
    for (int r = 0; r < 8; ++r)
        acc[r][0] = acc[r][1] = acc[r][2] = acc[r][3] = 0.f;

    for (int h = 0; h < HC_; h += 4) {
        float4 yv[4];
        #pragma unroll
        for (int q2 = 0; q2 < 4; ++q2)
            yv[q2] = *(const float4*)(yIn + (gp0 + q2) * HC_ + h);
        #pragma unroll
        for (int r = 0; r < 8; ++r) {
            float4 wv = *(const float4*)(Ww + (o0 + r) * HC_ + h);
            #pragma unroll
            for (int q2 = 0; q2 < 4; ++q2) {
                acc[r][q2] = fmaf(wv.x, yv[q2].x, acc[r][q2]);
                acc[r][q2] = fmaf(wv.y, yv[q2].y, acc[r][q2]);
                acc[r][q2] = fmaf(wv.z, yv[q2].z, acc[r][q2]);
                acc[r][q2] = fmaf(wv.w, yv[q2].w, acc[r][q2]);
            }
        }
    }
    #pragma unroll
    for (int r = 0; r < 8; ++r)
        #pragma unroll
        for (int q2 = 0; q2 < 4; ++q2) {
            int gp = gp0 + q2;
            int b = gp / HW_;
            int p = gp - b * HW_;
            wyO[(b * C_ + o0 + r) * HW_ + p] = acc[r][q2];
        }
}

// 5) BN batch stats per channel (biased var, N = B*HW = 4608), folded into
//    per-channel scale/shift.  grid = 256 (one block per channel)
__global__ __launch_bounds__(256) void bn_stats_kernel(
    const float* __restrict__ wy, const float* __restrict__ gamma,
    const float* __restrict__ beta, float2* __restrict__ stats)
{
    int o = blockIdx.x;
    int tid = threadIdx.x;
    float s = 0.f, s2 = 0.f;
    for (int idx = tid; idx < NP_; idx += 256) {
        int b = idx / HW_;
        int p = idx - b * HW_;
        float v = wy[(b * C_ + o) * HW_ + p];
        s += v;
        s2 = fmaf(v, v, s2);
    }
    #pragma unroll
    for (int off = 32; off; off >>= 1) {
        s  += __shfl_xor(s, off);
        s2 += __shfl_xor(s2, off);
    }
    __shared__ float ls[4], ls2[4];
    int wv = tid >> 6, lane = tid & 63;
    if (lane == 0) { ls[wv] = s; ls2[wv] = s2; }
    __syncthreads();
    if (tid == 0) {
        float S  = ls[0] + ls[1] + ls[2] + ls[3];
        float S2 = ls2[0] + ls2[1] + ls2[2] + ls2[3];
        float mean = S / (float)NP_;
        float var = fmaxf(S2 / (float)NP_ - mean * mean, 0.f);
        float rstd = rsqrtf(var + 1e-5f);
        float sc = gamma[o] * rstd;
        stats[o] = make_float2(sc, beta[o] - mean * sc);
    }
}

// 6) z = x + wy*scale + shift   (float4 elementwise)
//    grid = B*C*HW/4/256 = 1152
__global__ __launch_bounds__(256) void final_kernel(
    const float* __restrict__ x, const float* __restrict__ wy,
    const float2* __restrict__ stats, float* __restrict__ out)
{
    int idx = blockIdx.x * 256 + threadIdx.x;
    int e0 = idx * 4;
    int c = (e0 / HW_) & (C_ - 1);      // flat [B,C,HW]; HW%4==0 so c uniform in vec
    float2 st = stats[c];
    float4 xv = *(const float4*)(x + e0);
    float4 wv = *(const float4*)(wy + e0);
    float4 o;
    o.x = fmaf(wv.x, st.x, xv.x + st.y);
    o.y = fmaf(wv.y, st.x, xv.y + st.y);
    o.z = fmaf(wv.z, st.x, xv.z + st.y);
    o.w = fmaf(wv.w, st.x, xv.w + st.y);
    *(float4*)(out + e0) = o;
}

extern "C" void kernel_launch(void* const* d_in, const int* in_sizes, int n_in,
                              void* d_out, int out_size, void* d_ws, size_t ws_size,
                              hipStream_t stream) {
    const float* x       = (const float*)d_in[0];
    const float* ctx     = (const float*)d_in[1];
    const float* theta_w = (const float*)d_in[2];
    const float* psi_w   = (const float*)d_in[3];
    const float* g_w     = (const float*)d_in[4];
    const float* W_w     = (const float*)d_in[5];
    // d_in[6] = W_b: unused, cancels exactly under training-mode BN
    const float* gamma   = (const float*)d_in[7];
    const float* beta    = (const float*)d_in[8];
    float* out = (float*)d_out;

    float* ws   = (float*)d_ws;
    float* q    = ws;                       // [B,HW,128]      589824 f
    float* psi  = q   + 589824;             // [B,128,3,HW]  1769472 f
    float* g    = psi + 1769472;            // [B,3,HW,128]  1769472 f
    float* y    = g   + 1769472;            // [B,HW,128]     589824 f
    float* wy   = y   + 589824;             // [B,256,HW]    1179648 f
    float2* stats = (float2*)(wy + 1179648);// [256] float2

    proj_ctx_kernel<<<dim3(HW_ / 32, B_ * DC_), 256, 0, stream>>>(psi_w, g_w, ctx, psi, g);
    proj_q_kernel<<<dim3(HW_ / 64, B_), 256, 0, stream>>>(theta_w, x, q);
    attn_kernel<<<dim3(NP_ / 4), 256, 0, stream>>>(q, psi, g, y);
    wy_kernel<<<dim3(NP_ / 32), 256, 0, stream>>>(W_w, y, wy);
    bn_stats_kernel<<<dim3(C_), 256, 0, stream>>>(wy, gamma, beta, stats);
    final_kernel<<<dim3(B_ * C_ * HW_ / 4 / 256), 256, 0, stream>>>(x, wy, stats, out);
}

// Round 2
// 161.883 us; speedup vs baseline: 1.9301x; 1.9301x over previous
//
#include <hip/hip_runtime.h>
#include <cmath>

#define B_   2
#define C_   256
#define HC_  128
#define DC_  3
#define H_   48
#define W_   48
#define HW_  (H_ * W_)      // 2304
#define NP_  (B_ * HW_)     // 4608
#define K_   (DC_ * 49)     // 147
#define BK   32

// ---------------------------------------------------------------------------
// 1) Fused projection GEMM for psi, g, q.
//    Each block: 128 outs x 32 px, K=256 staged in BK=32 LDS chunks.
//    blocks 0..863:  psi/g over ctx  (id&1 selects psi vs g; adjacent blocks
//                    share the same ctx tile -> L2 reuse)
//    blocks 864..1007: q over x
//    psi layout: [B, 128, 3, HW]  (channel-major, for scores stage)
//    g   layout: [B, 3, HW, 128]  (channel-last, for PV stage)
//    q   layout: [B, HW, 128]
__global__ __launch_bounds__(256) void proj_all_kernel(
    const float* __restrict__ psi_w, const float* __restrict__ g_w,
    const float* __restrict__ theta_w,
    const float* __restrict__ ctx, const float* __restrict__ x,
    float* __restrict__ psiO, float* __restrict__ gO, float* __restrict__ qO)
{
    __shared__ float Wt[BK][HC_];    // [c][o], transposed at stage time
    __shared__ float Ct[BK][36];     // [c][px], padded 32->36

    int id = blockIdx.x;
    const float* w;
    const float* inp;
    int inStride, b, d, basep, mode;
    if (id < 864) {
        mode = id & 1;               // 0 = psi, 1 = g
        int rest = id >> 1;          // 0..431
        int pxt = rest % 72;
        int bd = rest / 72;
        b = bd / DC_; d = bd % DC_;
        basep = pxt * 32;
        w = mode ? g_w : psi_w;
        inp = ctx + (b * C_ * DC_ + d) * HW_;
        inStride = DC_ * HW_;
    } else {
        mode = 2;                    // q
        int id2 = id - 864;          // 0..143
        int pxt = id2 % 72;
        b = id2 / 72; d = 0;
        basep = pxt * 32;
        w = theta_w;
        inp = x + b * C_ * HW_;
        inStride = HW_;
    }

    int t = threadIdx.x;
    int og = t >> 3, pg = t & 7;
    int o0 = og * 4, p0 = pg * 4;

    // staging indices
    int wo = t >> 1;                 // 0..127 (one weight row per thread-pair)
    int wc = (t & 1) * 16;           // c-offset 0 or 16
    int cc = t >> 3;                 // 0..31
    int cp = (t & 7) * 4;

    float acc[4][4];
    #pragma unroll
    for (int r = 0; r < 4; ++r)
        acc[r][0] = acc[r][1] = acc[r][2] = acc[r][3] = 0.f;

    for (int c0 = 0; c0 < C_; c0 += BK) {
        __syncthreads();
        // stage weights transposed: Wt[c][o] <- w[o][c0+c]
        const float* wp = w + wo * C_ + c0 + wc;
        float4 wv4[4];
        wv4[0] = *(const float4*)(wp);
        wv4[1] = *(const float4*)(wp + 4);
        wv4[2] = *(const float4*)(wp + 8);
        wv4[3] = *(const float4*)(wp + 12);
        #pragma unroll
        for (int j = 0; j < 4; ++j) {
            Wt[wc + j * 4 + 0][wo] = wv4[j].x;
            Wt[wc + j * 4 + 1][wo] = wv4[j].y;
            Wt[wc + j * 4 + 2][wo] = wv4[j].z;
            Wt[wc + j * 4 + 3][wo] = wv4[j].w;
        }
        // stage input tile: Ct[c][px]
        float4 iv = *(const float4*)(inp + (c0 + cc) * inStride + basep + cp);
        *(float4*)&Ct[cc][cp] = iv;
        __syncthreads();

        #pragma unroll
        for (int c = 0; c < BK; ++c) {
            float4 wv = *(const float4*)&Wt[c][o0];
            float4 pv = *(const float4*)&Ct[c][p0];
            acc[0][0] = fmaf(wv.x, pv.x, acc[0][0]);
            acc[0][1] = fmaf(wv.x, pv.y, acc[0][1]);
            acc[0][2] = fmaf(wv.x, pv.z, acc[0][2]);
            acc[0][3] = fmaf(wv.x, pv.w, acc[0][3]);
            acc[1][0] = fmaf(wv.y, pv.x, acc[1][0]);
            acc[1][1] = fmaf(wv.y, pv.y, acc[1][1]);
            acc[1][2] = fmaf(wv.y, pv.z, acc[1][2]);
            acc[1][3] = fmaf(wv.y, pv.w, acc[1][3]);
            acc[2][0] = fmaf(wv.z, pv.x, acc[2][0]);
            acc[2][1] = fmaf(wv.z, pv.y, acc[2][1]);
            acc[2][2] = fmaf(wv.z, pv.z, acc[2][2]);
            acc[2][3] = fmaf(wv.z, pv.w, acc[2][3]);
            acc[3][0] = fmaf(wv.w, pv.x, acc[3][0]);
            acc[3][1] = fmaf(wv.w, pv.y, acc[3][1]);
            acc[3][2] = fmaf(wv.w, pv.z, acc[3][2]);
            acc[3][3] = fmaf(wv.w, pv.w, acc[3][3]);
        }
    }

    if (mode == 0) {
        // psi: channel-major [B,128,3,HW]
        #pragma unroll
        for (int r = 0; r < 4; ++r) {
            float4 v = make_float4(acc[r][0], acc[r][1], acc[r][2], acc[r][3]);
            *(float4*)(psiO + ((b * HC_ + o0 + r) * DC_ + d) * HW_ + basep + p0) = v;
        }
    } else {
        // g / q: channel-last
        float* outB = (mode == 1) ? (gO + (size_t)((b * DC_ + d) * HW_) * HC_)
                                  : (qO + (size_t)(b * HW_) * HC_);
        #pragma unroll
        for (int q2 = 0; q2 < 4; ++q2) {
            float4 v = make_float4(acc[0][q2], acc[1][q2], acc[2][q2], acc[3][q2]);
            *(float4*)(outB + (size_t)(basep + p0 + q2) * HC_ + o0) = v;
        }
    }
}

// ---------------------------------------------------------------------------
// 2) attention: one wave per pixel. Scores with lane=key, softmax via wave
//    shuffles, att transposed through LDS, PV with lane=channel.
// grid = NP/4, block = 256 (4 waves = 4 pixels)
__global__ __launch_bounds__(256) void attn_kernel(
    const float* __restrict__ q, const float* __restrict__ psi,
    const float* __restrict__ g, float* __restrict__ y)
{
    __shared__ float lds_att[4][192];
    int wv = threadIdx.x >> 6;
    int lane = threadIdx.x & 63;
    int gp = blockIdx.x * 4 + wv;       // global pixel, 0..4607
    int b = gp / HW_;
    int p = gp - b * HW_;
    int y0 = p / W_, x0 = p - y0 * W_;

    int offs[3];
    #pragma unroll
    for (int c2 = 0; c2 < 3; ++c2) {
        int k = c2 * 64 + lane;
        int kk = k < K_ ? k : (K_ - 1);
        int dd = (kk >= 98) ? 2 : (kk >= 49 ? 1 : 0);
        int r = kk - dd * 49;
        int i = (r >= 7) + (r >= 14) + (r >= 21) + (r >= 28) + (r >= 35) + (r >= 42);
        int j = r - i * 7;
        int ny = min(max(y0 + i - 3, 0), H_ - 1);
        int nx = min(max(x0 + j - 3, 0), W_ - 1);
        offs[c2] = dd * HW_ + ny * W_ + nx;
    }

    const float* psiB = psi + b * (HC_ * DC_ * HW_);
    const float* qB = q + (b * HW_ + p) * HC_;

    float s0 = 0.f, s1 = 0.f, s2 = 0.f;
    for (int h = 0; h < HC_; h += 4) {
        float4 qv = *(const float4*)(qB + h);
        #pragma unroll
        for (int u = 0; u < 4; ++u) {
            const float* pp = psiB + (h + u) * (DC_ * HW_);
            float qh = (u == 0) ? qv.x : (u == 1) ? qv.y : (u == 2) ? qv.z : qv.w;
            s0 = fmaf(qh, pp[offs[0]], s0);
            s1 = fmaf(qh, pp[offs[1]], s1);
            s2 = fmaf(qh, pp[offs[2]], s2);
        }
    }
    if (lane + 128 >= K_) s2 = -INFINITY;

    float m = fmaxf(fmaxf(s0, s1), s2);
    #pragma unroll
    for (int off = 32; off; off >>= 1) m = fmaxf(m, __shfl_xor(m, off));
    float e0 = __expf(s0 - m), e1 = __expf(s1 - m), e2 = __expf(s2 - m);
    float sum = e0 + e1 + e2;
    #pragma unroll
    for (int off = 32; off; off >>= 1) sum += __shfl_xor(sum, off);
    float inv = 1.0f / sum;

    lds_att[wv][lane]       = e0 * inv;
    lds_att[wv][64 + lane]  = e1 * inv;
    lds_att[wv][128 + lane] = e2 * inv;
    __syncthreads();

    const float* gB = g + b * (DC_ * HW_ * HC_);
    float a0 = 0.f, a1 = 0.f;
    for (int dd = 0; dd < DC_; ++dd) {
        #pragma unroll
        for (int i = 0; i < 7; ++i) {
            int ny = min(max(y0 + i - 3, 0), H_ - 1);
            #pragma unroll
            for (int j = 0; j < 7; ++j) {
                int nx = min(max(x0 + j - 3, 0), W_ - 1);
                float a = lds_att[wv][(dd * 7 + i) * 7 + j];
                const float* gp2 = gB + (dd * HW_ + ny * W_ + nx) * HC_;
                a0 = fmaf(a, gp2[lane], a0);
                a1 = fmaf(a, gp2[64 + lane], a1);
            }
        }
    }
    float* yp = y + (b * HW_ + p) * HC_;
    yp[lane] = a0;
    yp[64 + lane] = a1;
}

// ---------------------------------------------------------------------------
// 3) wy = W_w @ y  (W_b skipped: per-channel constant cancels under
//    training-mode BN).  wy layout [B, 256, HW].  grid = NP/32, block = 256
__global__ __launch_bounds__(256) void wy_kernel(
    const float* __restrict__ Ww, const float* __restrict__ yIn,
    float* __restrict__ wyO)
{
    int tid = threadIdx.x;
    int og = tid >> 3;
    int pg = tid & 7;
    int gp0 = blockIdx.x * 32 + pg * 4;
    int o0 = og * 8;

    float acc[8][4];
    #pragma unroll
    for (int r = 0; r < 8; ++r)
        acc[r][0] = acc[r][1] = acc[r][2] = acc[r][3] = 0.f;

    for (int h = 0; h < HC_; h += 4) {
        float4 yv[4];
        #pragma unroll
        for (int q2 = 0; q2 < 4; ++q2)
            yv[q2] = *(const float4*)(yIn + (gp0 + q2) * HC_ + h);
        #pragma unroll
        for (int r = 0; r < 8; ++r) {
            float4 wv = *(const float4*)(Ww + (o0 + r) * HC_ + h);
            #pragma unroll
            for (int q2 = 0; q2 < 4; ++q2) {
                acc[r][q2] = fmaf(wv.x, yv[q2].x, acc[r][q2]);
                acc[r][q2] = fmaf(wv.y, yv[q2].y, acc[r][q2]);
                acc[r][q2] = fmaf(wv.z, yv[q2].z, acc[r][q2]);
                acc[r][q2] = fmaf(wv.w, yv[q2].w, acc[r][q2]);
            }
        }
    }
    #pragma unroll
    for (int r = 0; r < 8; ++r)
        #pragma unroll
        for (int q2 = 0; q2 < 4; ++q2) {
            int gp = gp0 + q2;
            int b = gp / HW_;
            int p = gp - b * HW_;
            wyO[(b * C_ + o0 + r) * HW_ + p] = acc[r][q2];
        }
}

// ---------------------------------------------------------------------------
// 4) BN batch stats per channel -> folded scale/shift.  grid = 256
__global__ __launch_bounds__(256) void bn_stats_kernel(
    const float* __restrict__ wy, const float* __restrict__ gamma,
    const float* __restrict__ beta, float2* __restrict__ stats)
{
    int o = blockIdx.x;
    int tid = threadIdx.x;
    float s = 0.f, s2 = 0.f;
    for (int idx = tid; idx < NP_; idx += 256) {
        int b = idx / HW_;
        int p = idx - b * HW_;
        float v = wy[(b * C_ + o) * HW_ + p];
        s += v;
        s2 = fmaf(v, v, s2);
    }
    #pragma unroll
    for (int off = 32; off; off >>= 1) {
        s  += __shfl_xor(s, off);
        s2 += __shfl_xor(s2, off);
    }
    __shared__ float ls[4], ls2[4];
    int wv = tid >> 6, lane = tid & 63;
    if (lane == 0) { ls[wv] = s; ls2[wv] = s2; }
    __syncthreads();
    if (tid == 0) {
        float S  = ls[0] + ls[1] + ls[2] + ls[3];
        float S2 = ls2[0] + ls2[1] + ls2[2] + ls2[3];
        float mean = S / (float)NP_;
        float var = fmaxf(S2 / (float)NP_ - mean * mean, 0.f);
        float rstd = rsqrtf(var + 1e-5f);
        float sc = gamma[o] * rstd;
        stats[o] = make_float2(sc, beta[o] - mean * sc);
    }
}

// ---------------------------------------------------------------------------
// 5) z = x + wy*scale + shift
__global__ __launch_bounds__(256) void final_kernel(
    const float* __restrict__ x, const float* __restrict__ wy,
    const float2* __restrict__ stats, float* __restrict__ out)
{
    int idx = blockIdx.x * 256 + threadIdx.x;
    int e0 = idx * 4;
    int c = (e0 / HW_) & (C_ - 1);
    float2 st = stats[c];
    float4 xv = *(const float4*)(x + e0);
    float4 wv = *(const float4*)(wy + e0);
    float4 o;
    o.x = fmaf(wv.x, st.x, xv.x + st.y);
    o.y = fmaf(wv.y, st.x, xv.y + st.y);
    o.z = fmaf(wv.z, st.x, xv.z + st.y);
    o.w = fmaf(wv.w, st.x, xv.w + st.y);
    *(float4*)(out + e0) = o;
}

extern "C" void kernel_launch(void* const* d_in, const int* in_sizes, int n_in,
                              void* d_out, int out_size, void* d_ws, size_t ws_size,
                              hipStream_t stream) {
    const float* x       = (const float*)d_in[0];
    const float* ctx     = (const float*)d_in[1];
    const float* theta_w = (const float*)d_in[2];
    const float* psi_w   = (const float*)d_in[3];
    const float* g_w     = (const float*)d_in[4];
    const float* W_w     = (const float*)d_in[5];
    // d_in[6] = W_b: unused, cancels exactly under training-mode BN
    const float* gamma   = (const float*)d_in[7];
    const float* beta    = (const float*)d_in[8];
    float* out = (float*)d_out;

    float* ws   = (float*)d_ws;
    float* q    = ws;                       // [B,HW,128]      589824 f
    float* psi  = q   + 589824;             // [B,128,3,HW]  1769472 f
    float* g    = psi + 1769472;            // [B,3,HW,128]  1769472 f
    float* y    = g   + 1769472;            // [B,HW,128]     589824 f
    float* wy   = y   + 589824;             // [B,256,HW]    1179648 f
    float2* stats = (float2*)(wy + 1179648);// [256] float2

    proj_all_kernel<<<dim3(1008), 256, 0, stream>>>(psi_w, g_w, theta_w, ctx, x, psi, g, q);
    attn_kernel<<<dim3(NP_ / 4), 256, 0, stream>>>(q, psi, g, y);
    wy_kernel<<<dim3(NP_ / 32), 256, 0, stream>>>(W_w, y, wy);
    bn_stats_kernel<<<dim3(C_), 256, 0, stream>>>(wy, gamma, beta, stats);
    final_kernel<<<dim3(B_ * C_ * HW_ / 4 / 256), 256, 0, stream>>>(x, wy, stats, out);
}

// Round 4
// 110.114 us; speedup vs baseline: 2.8375x; 1.4701x over previous
//
#include <hip/hip_runtime.h>
#include <cmath>

#define B_   2
#define C_   256
#define HC_  128
#define DC_  3
#define H_   48
#define W_   48
#define HW_  (H_ * W_)      // 2304
#define NP_  (B_ * HW_)     // 4608
#define K_   (DC_ * 49)     // 147
#define BK   32
#define GW   64             // padded g width (col = x+3, 16B-aligned rows)

typedef __attribute__((ext_vector_type(8))) short bf16x8;
typedef __attribute__((ext_vector_type(4))) float f32x4;

__device__ inline unsigned short f2bf(float f) {
    union { float f; unsigned u; } v; v.f = f;
    unsigned r = v.u + 0x7FFF + ((v.u >> 16) & 1);
    return (unsigned short)(r >> 16);
}
__device__ inline float bf2f(unsigned short h) {
    union { unsigned u; float f; } v; v.u = ((unsigned)h) << 16;
    return v.f;
}

// ---------------------------------------------------------------------------
// 1) Fused projection GEMM for psi, g, q (LDS-tiled).
//    psiH/psiL: [B, 3, HW, 128] bf16 hi/lo split (MFMA B-frags for scores)
//    gP:        [B, 128, 3, 48, 64] bf16 (channel-major, x-padded: PV B-frag)
//    qH/qL:     [B, HW, 128] bf16 hi/lo split (MFMA A-frags)
__global__ __launch_bounds__(256) void proj_all_kernel(
    const float* __restrict__ psi_w, const float* __restrict__ g_w,
    const float* __restrict__ theta_w,
    const float* __restrict__ ctx, const float* __restrict__ x,
    unsigned short* __restrict__ psiH, unsigned short* __restrict__ psiL,
    unsigned short* __restrict__ gO,
    unsigned short* __restrict__ qH, unsigned short* __restrict__ qL)
{
    __shared__ float Wt[BK][HC_];
    __shared__ float Ct[BK][36];

    int id = blockIdx.x;
    const float* w;
    const float* inp;
    int inStride, b, d, basep, mode;
    if (id < 864) {
        mode = id & 1;               // 0 = psi, 1 = g
        int rest = id >> 1;
        int pxt = rest % 72;
        int bd = rest / 72;
        b = bd / DC_; d = bd % DC_;
        basep = pxt * 32;
        w = mode ? g_w : psi_w;
        inp = ctx + (b * C_ * DC_ + d) * HW_;
        inStride = DC_ * HW_;
    } else {
        mode = 2;                    // q
        int id2 = id - 864;
        int pxt = id2 % 72;
        b = id2 / 72; d = 0;
        basep = pxt * 32;
        w = theta_w;
        inp = x + b * C_ * HW_;
        inStride = HW_;
    }

    int t = threadIdx.x;
    int og = t >> 3, pg = t & 7;
    int o0 = og * 4, p0 = pg * 4;

    int wo = t >> 1;
    int wc = (t & 1) * 16;
    int cc = t >> 3;
    int cp = (t & 7) * 4;

    float acc[4][4];
    #pragma unroll
    for (int r = 0; r < 4; ++r)
        acc[r][0] = acc[r][1] = acc[r][2] = acc[r][3] = 0.f;

    for (int c0 = 0; c0 < C_; c0 += BK) {
        __syncthreads();
        const float* wp = w + wo * C_ + c0 + wc;
        float4 wv4[4];
        wv4[0] = *(const float4*)(wp);
        wv4[1] = *(const float4*)(wp + 4);
        wv4[2] = *(const float4*)(wp + 8);
        wv4[3] = *(const float4*)(wp + 12);
        #pragma unroll
        for (int j = 0; j < 4; ++j) {
            Wt[wc + j * 4 + 0][wo] = wv4[j].x;
            Wt[wc + j * 4 + 1][wo] = wv4[j].y;
            Wt[wc + j * 4 + 2][wo] = wv4[j].z;
            Wt[wc + j * 4 + 3][wo] = wv4[j].w;
        }
        float4 iv = *(const float4*)(inp + (c0 + cc) * inStride + basep + cp);
        *(float4*)&Ct[cc][cp] = iv;
        __syncthreads();

        #pragma unroll
        for (int c = 0; c < BK; ++c) {
            float4 wv = *(const float4*)&Wt[c][o0];
            float4 pv = *(const float4*)&Ct[c][p0];
            acc[0][0] = fmaf(wv.x, pv.x, acc[0][0]);
            acc[0][1] = fmaf(wv.x, pv.y, acc[0][1]);
            acc[0][2] = fmaf(wv.x, pv.z, acc[0][2]);
            acc[0][3] = fmaf(wv.x, pv.w, acc[0][3]);
            acc[1][0] = fmaf(wv.y, pv.x, acc[1][0]);
            acc[1][1] = fmaf(wv.y, pv.y, acc[1][1]);
            acc[1][2] = fmaf(wv.y, pv.z, acc[1][2]);
            acc[1][3] = fmaf(wv.y, pv.w, acc[1][3]);
            acc[2][0] = fmaf(wv.z, pv.x, acc[2][0]);
            acc[2][1] = fmaf(wv.z, pv.y, acc[2][1]);
            acc[2][2] = fmaf(wv.z, pv.z, acc[2][2]);
            acc[2][3] = fmaf(wv.z, pv.w, acc[2][3]);
            acc[3][0] = fmaf(wv.w, pv.x, acc[3][0]);
            acc[3][1] = fmaf(wv.w, pv.y, acc[3][1]);
            acc[3][2] = fmaf(wv.w, pv.z, acc[3][2]);
            acc[3][3] = fmaf(wv.w, pv.w, acc[3][3]);
        }
    }

    if (mode == 1) {
        // g channel-major padded: [b][o][d][y][64], col = x+3, scalar stores
        #pragma unroll
        for (int r = 0; r < 4; ++r) {
            #pragma unroll
            for (int q2 = 0; q2 < 4; ++q2) {
                int p = basep + p0 + q2;
                int yy = p / W_, xx = p - yy * W_;
                gO[(((size_t)(b * HC_ + o0 + r) * DC_ + d) * H_ + yy) * GW + xx + 3]
                    = f2bf(acc[r][q2]);
            }
        }
    } else {
        unsigned short* outH = (mode == 0)
            ? (psiH + (size_t)((b * DC_ + d) * HW_) * HC_)
            : (qH + (size_t)(b * HW_) * HC_);
        unsigned short* outL = (mode == 0)
            ? (psiL + (size_t)((b * DC_ + d) * HW_) * HC_)
            : (qL + (size_t)(b * HW_) * HC_);
        #pragma unroll
        for (int q2 = 0; q2 < 4; ++q2) {
            ushort4 vh, vl;
            float f;
            f = acc[0][q2]; vh.x = f2bf(f); vl.x = f2bf(f - bf2f(vh.x));
            f = acc[1][q2]; vh.y = f2bf(f); vl.y = f2bf(f - bf2f(vh.y));
            f = acc[2][q2]; vh.z = f2bf(f); vl.z = f2bf(f - bf2f(vh.z));
            f = acc[3][q2]; vh.w = f2bf(f); vl.w = f2bf(f - bf2f(vh.w));
            *(ushort4*)(outH + (size_t)(basep + p0 + q2) * HC_ + o0) = vh;
            *(ushort4*)(outL + (size_t)(basep + p0 + q2) * HC_ + o0) = vl;
        }
    }
}

// ---------------------------------------------------------------------------
// 1b) replicate-pad g rows: cols 0..2 <- col 3 (x=0), cols 51..63 <- col 50 (x=47)
__global__ __launch_bounds__(256) void pad_g_kernel(unsigned short* __restrict__ gP)
{
    int row = blockIdx.x * 256 + threadIdx.x;   // B*HC*DC*H = 36864 rows
    if (row >= B_ * HC_ * DC_ * H_) return;
    unsigned short* r = gP + (size_t)row * GW;
    unsigned short lo = r[3], hi = r[50];
    r[0] = lo; r[1] = lo; r[2] = lo;
    #pragma unroll
    for (int t = 51; t < GW; ++t) r[t] = hi;
}

// ---------------------------------------------------------------------------
// 2) MFMA band-GEMM attention with compensated-bf16 scores.
//    S = qh*ph + qh*pl + ql*ph  (error ~2^-17 relative)
__global__ __launch_bounds__(512) void attn_mfma_kernel(
    const unsigned short* __restrict__ qHp, const unsigned short* __restrict__ qLp,
    const unsigned short* __restrict__ psiHp, const unsigned short* __restrict__ psiLp,
    const unsigned short* __restrict__ g, float* __restrict__ y)
{
    __shared__ float S[147 * 17];

    int bid = blockIdx.x;
    int tile = (bid & 7) * 36 + (bid >> 3);   // XCD-contiguous pixel rows
    int b = tile / 144;
    int tr = tile - b * 144;
    int y0 = tr / 3;
    int x0 = (tr % 3) * 16;

    int t = threadIdx.x;
    int w = t >> 6;           // wave 0..7
    int l = t & 63;
    int lc = l & 15;
    int grp = l >> 4;
    int pixBase = b * HW_ + y0 * W_ + x0;

    // Q A-frags (hi and lo): lane holds row p=lc, k = ks*32 + grp*8 + 0..7
    const unsigned short* qrowH = qHp + (size_t)(pixBase + lc) * HC_ + grp * 8;
    const unsigned short* qrowL = qLp + (size_t)(pixBase + lc) * HC_ + grp * 8;
    bf16x8 qh[4], ql[4];
    #pragma unroll
    for (int ks = 0; ks < 4; ++ks) {
        qh[ks] = *(const bf16x8*)(qrowH + ks * 32);
        ql[ks] = *(const bf16x8*)(qrowL + ks * 32);
    }

    // ---- scores ----
    for (int idx = w; idx < 21; idx += 8) {
        int d = idx / 7, i = idx - 7 * d;
        int ry = min(max(y0 + i - 3, 0), H_ - 1);
        size_t rowOff = ((size_t)(b * DC_ + d) * HW_ + ry * W_) * HC_;
        const unsigned short* psiRowH = psiHp + rowOff;
        const unsigned short* psiRowL = psiLp + rowOff;
        #pragma unroll
        for (int f = 0; f < 2; ++f) {
            int c = f * 16 + lc;
            int px = min(max(x0 + c - 3, 0), W_ - 1);
            const unsigned short* bpH = psiRowH + (size_t)px * HC_ + grp * 8;
            const unsigned short* bpL = psiRowL + (size_t)px * HC_ + grp * 8;
            f32x4 acc = {0.f, 0.f, 0.f, 0.f};
            #pragma unroll
            for (int ks = 0; ks < 4; ++ks) {
                bf16x8 ph = *(const bf16x8*)(bpH + ks * 32);
                bf16x8 pl = *(const bf16x8*)(bpL + ks * 32);
                acc = __builtin_amdgcn_mfma_f32_16x16x32_bf16(qh[ks], ph, acc, 0, 0, 0);
                acc = __builtin_amdgcn_mfma_f32_16x16x32_bf16(qh[ks], pl, acc, 0, 0, 0);
                acc = __builtin_amdgcn_mfma_f32_16x16x32_bf16(ql[ks], ph, acc, 0, 0, 0);
            }
            #pragma unroll
            for (int r = 0; r < 4; ++r) {
                int p = grp * 4 + r;      // C/D: row=(lane>>4)*4+reg, col=lane&15
                int j = c - p;
                if (j >= 0 && j < 7) S[(idx * 7 + j) * 17 + p] = acc[r];
            }
        }
    }
    __syncthreads();

    // ---- softmax (wave w owns pixels 2w, 2w+1; lane = key chunk) ----
    #pragma unroll
    for (int pi = 0; pi < 2; ++pi) {
        int p = w * 2 + pi;
        float s0 = S[l * 17 + p];
        float s1 = S[(64 + l) * 17 + p];
        float s2 = (l + 128 < K_) ? S[(128 + l) * 17 + p] : -1e30f;
        float m = fmaxf(fmaxf(s0, s1), s2);
        #pragma unroll
        for (int off = 32; off; off >>= 1) m = fmaxf(m, __shfl_xor(m, off));
        float e0 = __expf(s0 - m), e1 = __expf(s1 - m), e2 = __expf(s2 - m);
        float sum = e0 + e1 + e2;
        #pragma unroll
        for (int off = 32; off; off >>= 1) sum += __shfl_xor(sum, off);
        float inv = 1.0f / sum;
        S[l * 17 + p] = e0 * inv;
        S[(64 + l) * 17 + p] = e1 * inv;
        if (l + 128 < K_) S[(128 + l) * 17 + p] = e2 * inv;
    }
    __syncthreads();

    // ---- PV: wave w owns output h-tile w (h = 16w + lc) ----
    int hB = w * 16 + lc;
    f32x4 acc = {0.f, 0.f, 0.f, 0.f};
    for (int idx = 0; idx < 21; ++idx) {
        int d = idx / 7, i = idx - 7 * d;
        int ry = min(max(y0 + i - 3, 0), H_ - 1);
        // A-frag: row p = lc, k(col c) = grp*8 + r; val = att[p][(d,i,j=c-p)]
        unsigned au[4];
        #pragma unroll
        for (int rr = 0; rr < 4; ++rr) {
            int k0 = grp * 8 + rr * 2;
            int j0 = k0 - lc, j1 = k0 + 1 - lc;
            float v0 = (j0 >= 0 && j0 < 7) ? S[(idx * 7 + j0) * 17 + lc] : 0.f;
            float v1 = (j1 >= 0 && j1 < 7) ? S[(idx * 7 + j1) * 17 + lc] : 0.f;
            au[rr] = (unsigned)f2bf(v0) | ((unsigned)f2bf(v1) << 16);
        }
        union { unsigned u[4]; bf16x8 v; } af;
        af.u[0] = au[0]; af.u[1] = au[1]; af.u[2] = au[2]; af.u[3] = au[3];
        // B-frag: col n = h (lane), k = 8 consecutive padded-x cols
        const unsigned short* gb = g
            + (((size_t)(b * HC_ + hB) * DC_ + d) * H_ + ry) * GW + x0 + grp * 8;
        bf16x8 bg = *(const bf16x8*)gb;
        acc = __builtin_amdgcn_mfma_f32_16x16x32_bf16(af.v, bg, acc, 0, 0, 0);
    }
    #pragma unroll
    for (int r = 0; r < 4; ++r) {
        int p = grp * 4 + r;
        y[(size_t)(pixBase + p) * HC_ + hB] = acc[r];
    }
}

// ---------------------------------------------------------------------------
// 3) wy = W_w @ y  (W_b cancels under training-mode BN). [B,256,HW]
__global__ __launch_bounds__(256) void wy_kernel(
    const float* __restrict__ Ww, const float* __restrict__ yIn,
    float* __restrict__ wyO)
{
    int tid = threadIdx.x;
    int og = tid >> 3;
    int pg = tid & 7;
    int gp0 = blockIdx.x * 32 + pg * 4;
    int o0 = og * 8;

    float acc[8][4];
    #pragma unroll
    for (int r = 0; r < 8; ++r)
        acc[r][0] = acc[r][1] = acc[r][2] = acc[r][3] = 0.f;

    for (int h = 0; h < HC_; h += 4) {
        float4 yv[4];
        #pragma unroll
        for (int q2 = 0; q2 < 4; ++q2)
            yv[q2] = *(const float4*)(yIn + (gp0 + q2) * HC_ + h);
        #pragma unroll
        for (int r = 0; r < 8; ++r) {
            float4 wv = *(const float4*)(Ww + (o0 + r) * HC_ + h);
            #pragma unroll
            for (int q2 = 0; q2 < 4; ++q2) {
                acc[r][q2] = fmaf(wv.x, yv[q2].x, acc[r][q2]);
                acc[r][q2] = fmaf(wv.y, yv[q2].y, acc[r][q2]);
                acc[r][q2] = fmaf(wv.z, yv[q2].z, acc[r][q2]);
                acc[r][q2] = fmaf(wv.w, yv[q2].w, acc[r][q2]);
            }
        }
    }
    #pragma unroll
    for (int r = 0; r < 8; ++r)
        #pragma unroll
        for (int q2 = 0; q2 < 4; ++q2) {
            int gp = gp0 + q2;
            int b = gp / HW_;
            int p = gp - b * HW_;
            wyO[(b * C_ + o0 + r) * HW_ + p] = acc[r][q2];
        }
}

// ---------------------------------------------------------------------------
// 4) BN batch stats per channel -> folded scale/shift.  grid = 256
__global__ __launch_bounds__(256) void bn_stats_kernel(
    const float* __restrict__ wy, const float* __restrict__ gamma,
    const float* __restrict__ beta, float2* __restrict__ stats)
{
    int o = blockIdx.x;
    int tid = threadIdx.x;
    float s = 0.f, s2 = 0.f;
    for (int idx = tid; idx < NP_; idx += 256) {
        int b = idx / HW_;
        int p = idx - b * HW_;
        float v = wy[(b * C_ + o) * HW_ + p];
        s += v;
        s2 = fmaf(v, v, s2);
    }
    #pragma unroll
    for (int off = 32; off; off >>= 1) {
        s  += __shfl_xor(s, off);
        s2 += __shfl_xor(s2, off);
    }
    __shared__ float ls[4], ls2[4];
    int wv = tid >> 6, lane = tid & 63;
    if (lane == 0) { ls[wv] = s; ls2[wv] = s2; }
    __syncthreads();
    if (tid == 0) {
        float S  = ls[0] + ls[1] + ls[2] + ls[3];
        float S2 = ls2[0] + ls2[1] + ls2[2] + ls2[3];
        float mean = S / (float)NP_;
        float var = fmaxf(S2 / (float)NP_ - mean * mean, 0.f);
        float rstd = rsqrtf(var + 1e-5f);
        float sc = gamma[o] * rstd;
        stats[o] = make_float2(sc, beta[o] - mean * sc);
    }
}

// ---------------------------------------------------------------------------
// 5) z = x + wy*scale + shift
__global__ __launch_bounds__(256) void final_kernel(
    const float* __restrict__ x, const float* __restrict__ wy,
    const float2* __restrict__ stats, float* __restrict__ out)
{
    int idx = blockIdx.x * 256 + threadIdx.x;
    int e0 = idx * 4;
    int c = (e0 / HW_) & (C_ - 1);
    float2 st = stats[c];
    float4 xv = *(const float4*)(x + e0);
    float4 wv = *(const float4*)(wy + e0);
    float4 o;
    o.x = fmaf(wv.x, st.x, xv.x + st.y);
    o.y = fmaf(wv.y, st.x, xv.y + st.y);
    o.z = fmaf(wv.z, st.x, xv.z + st.y);
    o.w = fmaf(wv.w, st.x, xv.w + st.y);
    *(float4*)(out + e0) = o;
}

extern "C" void kernel_launch(void* const* d_in, const int* in_sizes, int n_in,
                              void* d_out, int out_size, void* d_ws, size_t ws_size,
                              hipStream_t stream) {
    const float* x       = (const float*)d_in[0];
    const float* ctx     = (const float*)d_in[1];
    const float* theta_w = (const float*)d_in[2];
    const float* psi_w   = (const float*)d_in[3];
    const float* g_w     = (const float*)d_in[4];
    const float* W_w     = (const float*)d_in[5];
    // d_in[6] = W_b: unused, cancels exactly under training-mode BN
    const float* gamma   = (const float*)d_in[7];
    const float* beta    = (const float*)d_in[8];
    float* out = (float*)d_out;

    unsigned short* qH   = (unsigned short*)d_ws;   // [B,HW,128] bf16      589824
    unsigned short* qL   = qH + 589824;             // [B,HW,128] bf16      589824
    unsigned short* psiH = qL + 589824;             // [B,3,HW,128] bf16   1769472
    unsigned short* psiL = psiH + 1769472;          // [B,3,HW,128] bf16   1769472
    unsigned short* gB   = psiL + 1769472;          // [B,128,3,48,64]     4718592
    float* yB  = (float*)(gB + 4718592);            // [B,HW,128] f32       589824
    float* wyB = yB + 589824;                       // [B,256,HW] f32      1179648
    float2* stats = (float2*)(wyB + 1179648);       // [256]

    proj_all_kernel<<<dim3(1008), 256, 0, stream>>>(psi_w, g_w, theta_w, ctx, x,
                                                    psiH, psiL, gB, qH, qL);
    pad_g_kernel<<<dim3(144), 256, 0, stream>>>(gB);
    attn_mfma_kernel<<<dim3(288), 512, 0, stream>>>(qH, qL, psiH, psiL, gB, yB);
    wy_kernel<<<dim3(NP_ / 32), 256, 0, stream>>>(W_w, yB, wyB);
    bn_stats_kernel<<<dim3(C_), 256, 0, stream>>>(wyB, gamma, beta, stats);
    final_kernel<<<dim3(B_ * C_ * HW_ / 4 / 256), 256, 0, stream>>>(x, wyB, stats, out);
}

// Round 5
// 106.254 us; speedup vs baseline: 2.9406x; 1.0363x over previous
//
#include <hip/hip_runtime.h>
#include <cmath>

#define B_   2
#define C_   256
#define HC_  128
#define DC_  3
#define H_   48
#define W_   48
#define HW_  (H_ * W_)      // 2304
#define NP_  (B_ * HW_)     // 4608
#define K_   (DC_ * 49)     // 147
#define GW   64             // padded g width (col = x+3, 16B-aligned rows)

typedef __attribute__((ext_vector_type(8))) short bf16x8;
typedef __attribute__((ext_vector_type(4))) float f32x4;

__device__ inline unsigned short f2bf(float f) {
    union { float f; unsigned u; } v; v.f = f;
    unsigned r = v.u + 0x7FFF + ((v.u >> 16) & 1);
    return (unsigned short)(r >> 16);
}
__device__ inline float bf2f(unsigned short h) {
    union { unsigned u; float f; } v; v.u = ((unsigned)h) << 16;
    return v.f;
}

// ---------------------------------------------------------------------------
// 0) split weights into bf16 hi/lo planes.
//    Wpg = [psi_w; g_w] stacked [256][256]; Wq = theta [128][256]; Ww [256][128]
__global__ __launch_bounds__(256) void split_w_kernel(
    const float* __restrict__ psi_w, const float* __restrict__ g_w,
    const float* __restrict__ theta_w, const float* __restrict__ Ww,
    unsigned short* __restrict__ WpgH, unsigned short* __restrict__ WpgL,
    unsigned short* __restrict__ WqH, unsigned short* __restrict__ WqL,
    unsigned short* __restrict__ WwH, unsigned short* __restrict__ WwL)
{
    int idx = (blockIdx.x * 256 + threadIdx.x) * 4;   // grid 128 -> 131072 elems
    float4 v;
    unsigned short *dH, *dL;
    if (idx < 65536) {
        v = *(const float4*)(idx < 32768 ? psi_w + idx : g_w + (idx - 32768));
        dH = WpgH + idx; dL = WpgL + idx;
    } else if (idx < 98304) {
        v = *(const float4*)(theta_w + idx - 65536);
        dH = WqH + idx - 65536; dL = WqL + idx - 65536;
    } else {
        v = *(const float4*)(Ww + idx - 98304);
        dH = WwH + idx - 98304; dL = WwL + idx - 98304;
    }
    ushort4 h, l;
    h.x = f2bf(v.x); l.x = f2bf(v.x - bf2f(h.x));
    h.y = f2bf(v.y); l.y = f2bf(v.y - bf2f(h.y));
    h.z = f2bf(v.z); l.z = f2bf(v.z - bf2f(h.z));
    h.w = f2bf(v.w); l.w = f2bf(v.w - bf2f(h.w));
    *(ushort4*)dH = h; *(ushort4*)dL = l;
}

// ---------------------------------------------------------------------------
// 1) MFMA projection for psi+g (stacked, ctx input) and q (x input).
//    Compensated bf16: acc = Wh*Xh + Wh*Xl + Wl*Xh  (err ~2^-17)
//    LDS: X transposed [plane][px 32][c 256] ushort, 16B-chunk XOR swizzle.
//    blocks 0..431: ctx-mode ((b,d) x 72 px-tiles), 432..575: q-mode.
__global__ __launch_bounds__(512) void proj_mfma_kernel(
    const unsigned short* __restrict__ WpgH, const unsigned short* __restrict__ WpgL,
    const unsigned short* __restrict__ WqH, const unsigned short* __restrict__ WqL,
    const float* __restrict__ ctx, const float* __restrict__ x,
    unsigned short* __restrict__ psiH, unsigned short* __restrict__ psiL,
    unsigned short* __restrict__ gO,
    unsigned short* __restrict__ qH, unsigned short* __restrict__ qL)
{
    __shared__ unsigned short Xl[2][32][256];   // 32 KB

    int id = blockIdx.x;
    int t = threadIdx.x;
    int mode, b, d, basep;
    const float* inp; int inStride;
    const unsigned short *WH, *WL;
    if (id < 432) {
        mode = 0;
        int pxt = id % 72; int bd = id / 72;
        b = bd / DC_; d = bd % DC_;
        basep = pxt * 32;
        inp = ctx + (size_t)(b * C_ * DC_ + d) * HW_;
        inStride = DC_ * HW_;
        WH = WpgH; WL = WpgL;
    } else {
        mode = 1;
        int id2 = id - 432;
        int pxt = id2 % 72; b = id2 / 72; d = 0;
        basep = pxt * 32;
        inp = x + (size_t)b * C_ * HW_;
        inStride = HW_;
        WH = WqH; WL = WqL;
    }

    // ---- stage: read [c][px] f32, write transposed hi/lo bf16 w/ swizzle ----
    {
        int crow = (t >> 4) * 2;        // 0..62 even
        int px2 = (t & 15) * 2;         // 0..30 even
        #pragma unroll
        for (int r = 0; r < 4; ++r) {
            int c = r * 64 + crow;
            float2 v0 = *(const float2*)(inp + (size_t)c * inStride + basep + px2);
            float2 v1 = *(const float2*)(inp + (size_t)(c + 1) * inStride + basep + px2);
            unsigned short h00 = f2bf(v0.x), h01 = f2bf(v0.y);
            unsigned short h10 = f2bf(v1.x), h11 = f2bf(v1.y);
            unsigned short l00 = f2bf(v0.x - bf2f(h00)), l01 = f2bf(v0.y - bf2f(h01));
            unsigned short l10 = f2bf(v1.x - bf2f(h10)), l11 = f2bf(v1.y - bf2f(h11));
            int kc = c >> 3, off = c & 7;
            int col0 = ((kc ^ (px2 & 7)) << 3) | off;           // row px2
            int col1 = ((kc ^ ((px2 + 1) & 7)) << 3) | off;     // row px2+1
            *(unsigned*)&Xl[0][px2][col0]     = (unsigned)h00 | ((unsigned)h10 << 16);
            *(unsigned*)&Xl[0][px2 + 1][col1] = (unsigned)h01 | ((unsigned)h11 << 16);
            *(unsigned*)&Xl[1][px2][col0]     = (unsigned)l00 | ((unsigned)l10 << 16);
            *(unsigned*)&Xl[1][px2 + 1][col1] = (unsigned)l01 | ((unsigned)l11 << 16);
        }
    }
    __syncthreads();

    int l = t & 63, w = t >> 6;
    int lc = l & 15, grp = l >> 4;
    int pxt = w & 1;
    int rowL = pxt * 16 + lc;          // px within 32-tile
    int rsw = rowL & 7;
    int p = basep + rowL;              // pixel within image

    // B-frags once per wave (X: col=px, k=c)
    bf16x8 bH[8], bL[8];
    #pragma unroll
    for (int ks = 0; ks < 8; ++ks) {
        int colc = ((ks * 4 + grp) ^ rsw) << 3;
        bH[ks] = *(const bf16x8*)&Xl[0][rowL][colc];
        bL[ks] = *(const bf16x8*)&Xl[1][rowL][colc];
    }

    int nOT = mode ? 2 : 4;
    int otBase = (w >> 1) * nOT;
    for (int oi = 0; oi < nOT; ++oi) {
        int ot = otBase + oi;
        const unsigned short* wrH = WH + (size_t)(ot * 16 + lc) * 256 + grp * 8;
        const unsigned short* wrL = WL + (size_t)(ot * 16 + lc) * 256 + grp * 8;
        f32x4 acc = {0.f, 0.f, 0.f, 0.f};
        #pragma unroll
        for (int ks = 0; ks < 8; ++ks) {
            bf16x8 aH = *(const bf16x8*)(wrH + ks * 32);
            bf16x8 aL = *(const bf16x8*)(wrL + ks * 32);
            acc = __builtin_amdgcn_mfma_f32_16x16x32_bf16(aH, bH[ks], acc, 0, 0, 0);
            acc = __builtin_amdgcn_mfma_f32_16x16x32_bf16(aH, bL[ks], acc, 0, 0, 0);
            acc = __builtin_amdgcn_mfma_f32_16x16x32_bf16(aL, bH[ks], acc, 0, 0, 0);
        }
        // D: row(o) = 4*grp + reg, col(px) = lc
        if (mode == 0) {
            if (ot < 8) {               // psi channels, hi/lo channel-last
                int o0 = ot * 16 + grp * 4;
                ushort4 vh, vl;
                vh.x = f2bf(acc[0]); vl.x = f2bf(acc[0] - bf2f(vh.x));
                vh.y = f2bf(acc[1]); vl.y = f2bf(acc[1] - bf2f(vh.y));
                vh.z = f2bf(acc[2]); vl.z = f2bf(acc[2] - bf2f(vh.z));
                vh.w = f2bf(acc[3]); vl.w = f2bf(acc[3] - bf2f(vh.w));
                size_t base = ((size_t)(b * DC_ + d) * HW_ + p) * HC_ + o0;
                *(ushort4*)&psiH[base] = vh;
                *(ushort4*)&psiL[base] = vl;
            } else {                    // g channels, single bf16 padded layout
                int o0 = (ot - 8) * 16 + grp * 4;
                int yy = p / W_, xx = p - yy * W_;
                #pragma unroll
                for (int r2 = 0; r2 < 4; ++r2)
                    gO[(((size_t)(b * HC_ + o0 + r2) * DC_ + d) * H_ + yy) * GW + xx + 3]
                        = f2bf(acc[r2]);
            }
        } else {
            int o0 = ot * 16 + grp * 4;
            ushort4 vh, vl;
            vh.x = f2bf(acc[0]); vl.x = f2bf(acc[0] - bf2f(vh.x));
            vh.y = f2bf(acc[1]); vl.y = f2bf(acc[1] - bf2f(vh.y));
            vh.z = f2bf(acc[2]); vl.z = f2bf(acc[2] - bf2f(vh.z));
            vh.w = f2bf(acc[3]); vl.w = f2bf(acc[3] - bf2f(vh.w));
            size_t base = ((size_t)b * HW_ + p) * HC_ + o0;
            *(ushort4*)&qH[base] = vh;
            *(ushort4*)&qL[base] = vl;
        }
    }
}

// ---------------------------------------------------------------------------
// 1b) replicate-pad g rows: cols 0..2 <- col 3 (x=0), cols 51..63 <- col 50 (x=47)
__global__ __launch_bounds__(256) void pad_g_kernel(unsigned short* __restrict__ gP)
{
    int row = blockIdx.x * 256 + threadIdx.x;   // B*HC*DC*H = 36864 rows
    if (row >= B_ * HC_ * DC_ * H_) return;
    unsigned short* r = gP + (size_t)row * GW;
    unsigned short lo = r[3], hi = r[50];
    r[0] = lo; r[1] = lo; r[2] = lo;
    #pragma unroll
    for (int t = 51; t < GW; ++t) r[t] = hi;
}

// ---------------------------------------------------------------------------
// 2) MFMA band-GEMM attention with compensated-bf16 scores.
//    y written as bf16 hi/lo channel-last (feeds wy MFMA B-frags directly).
__global__ __launch_bounds__(512) void attn_mfma_kernel(
    const unsigned short* __restrict__ qHp, const unsigned short* __restrict__ qLp,
    const unsigned short* __restrict__ psiHp, const unsigned short* __restrict__ psiLp,
    const unsigned short* __restrict__ g,
    unsigned short* __restrict__ yH, unsigned short* __restrict__ yL)
{
    __shared__ float S[147 * 17];

    int bid = blockIdx.x;
    int tile = (bid & 7) * 36 + (bid >> 3);   // XCD-contiguous pixel rows
    int b = tile / 144;
    int tr = tile - b * 144;
    int y0 = tr / 3;
    int x0 = (tr % 3) * 16;

    int t = threadIdx.x;
    int w = t >> 6;
    int l = t & 63;
    int lc = l & 15;
    int grp = l >> 4;
    int pixBase = b * HW_ + y0 * W_ + x0;

    const unsigned short* qrowH = qHp + (size_t)(pixBase + lc) * HC_ + grp * 8;
    const unsigned short* qrowL = qLp + (size_t)(pixBase + lc) * HC_ + grp * 8;
    bf16x8 qh[4], ql[4];
    #pragma unroll
    for (int ks = 0; ks < 4; ++ks) {
        qh[ks] = *(const bf16x8*)(qrowH + ks * 32);
        ql[ks] = *(const bf16x8*)(qrowL + ks * 32);
    }

    // ---- scores ----
    for (int idx = w; idx < 21; idx += 8) {
        int d = idx / 7, i = idx - 7 * d;
        int ry = min(max(y0 + i - 3, 0), H_ - 1);
        size_t rowOff = ((size_t)(b * DC_ + d) * HW_ + ry * W_) * HC_;
        const unsigned short* psiRowH = psiHp + rowOff;
        const unsigned short* psiRowL = psiLp + rowOff;
        #pragma unroll
        for (int f = 0; f < 2; ++f) {
            int c = f * 16 + lc;
            int px = min(max(x0 + c - 3, 0), W_ - 1);
            const unsigned short* bpH = psiRowH + (size_t)px * HC_ + grp * 8;
            const unsigned short* bpL = psiRowL + (size_t)px * HC_ + grp * 8;
            f32x4 acc = {0.f, 0.f, 0.f, 0.f};
            #pragma unroll
            for (int ks = 0; ks < 4; ++ks) {
                bf16x8 ph = *(const bf16x8*)(bpH + ks * 32);
                bf16x8 pl = *(const bf16x8*)(bpL + ks * 32);
                acc = __builtin_amdgcn_mfma_f32_16x16x32_bf16(qh[ks], ph, acc, 0, 0, 0);
                acc = __builtin_amdgcn_mfma_f32_16x16x32_bf16(qh[ks], pl, acc, 0, 0, 0);
                acc = __builtin_amdgcn_mfma_f32_16x16x32_bf16(ql[ks], ph, acc, 0, 0, 0);
            }
            #pragma unroll
            for (int r = 0; r < 4; ++r) {
                int p = grp * 4 + r;
                int j = c - p;
                if (j >= 0 && j < 7) S[(idx * 7 + j) * 17 + p] = acc[r];
            }
        }
    }
    __syncthreads();

    // ---- softmax ----
    #pragma unroll
    for (int pi = 0; pi < 2; ++pi) {
        int p = w * 2 + pi;
        float s0 = S[l * 17 + p];
        float s1 = S[(64 + l) * 17 + p];
        float s2 = (l + 128 < K_) ? S[(128 + l) * 17 + p] : -1e30f;
        float m = fmaxf(fmaxf(s0, s1), s2);
        #pragma unroll
        for (int off = 32; off; off >>= 1) m = fmaxf(m, __shfl_xor(m, off));
        float e0 = __expf(s0 - m), e1 = __expf(s1 - m), e2 = __expf(s2 - m);
        float sum = e0 + e1 + e2;
        #pragma unroll
        for (int off = 32; off; off >>= 1) sum += __shfl_xor(sum, off);
        float inv = 1.0f / sum;
        S[l * 17 + p] = e0 * inv;
        S[(64 + l) * 17 + p] = e1 * inv;
        if (l + 128 < K_) S[(128 + l) * 17 + p] = e2 * inv;
    }
    __syncthreads();

    // ---- PV ----
    int hB = w * 16 + lc;
    f32x4 acc = {0.f, 0.f, 0.f, 0.f};
    for (int idx = 0; idx < 21; ++idx) {
        int d = idx / 7, i = idx - 7 * d;
        int ry = min(max(y0 + i - 3, 0), H_ - 1);
        unsigned au[4];
        #pragma unroll
        for (int rr = 0; rr < 4; ++rr) {
            int k0 = grp * 8 + rr * 2;
            int j0 = k0 - lc, j1 = k0 + 1 - lc;
            float v0 = (j0 >= 0 && j0 < 7) ? S[(idx * 7 + j0) * 17 + lc] : 0.f;
            float v1 = (j1 >= 0 && j1 < 7) ? S[(idx * 7 + j1) * 17 + lc] : 0.f;
            au[rr] = (unsigned)f2bf(v0) | ((unsigned)f2bf(v1) << 16);
        }
        union { unsigned u[4]; bf16x8 v; } af;
        af.u[0] = au[0]; af.u[1] = au[1]; af.u[2] = au[2]; af.u[3] = au[3];
        const unsigned short* gb = g
            + (((size_t)(b * HC_ + hB) * DC_ + d) * H_ + ry) * GW + x0 + grp * 8;
        bf16x8 bg = *(const bf16x8*)gb;
        acc = __builtin_amdgcn_mfma_f32_16x16x32_bf16(af.v, bg, acc, 0, 0, 0);
    }
    #pragma unroll
    for (int r = 0; r < 4; ++r) {
        int p = grp * 4 + r;
        size_t o = (size_t)(pixBase + p) * HC_ + hB;
        float v = acc[r];
        unsigned short hh = f2bf(v);
        yH[o] = hh;
        yL[o] = f2bf(v - bf2f(hh));
    }
}

// ---------------------------------------------------------------------------
// 3) wy = W_w @ y via MFMA, compensated bf16. B-frags load straight from
//    global (y is channel-last hi/lo). No LDS. wy layout [B,256,HW] f32.
__global__ __launch_bounds__(512) void wy_mfma_kernel(
    const unsigned short* __restrict__ WwH, const unsigned short* __restrict__ WwL,
    const unsigned short* __restrict__ yHp, const unsigned short* __restrict__ yLp,
    float* __restrict__ wyO)
{
    int blk = blockIdx.x;              // 144
    int t = threadIdx.x;
    int l = t & 63, w = t >> 6;
    int lc = l & 15, grp = l >> 4;
    int pxg = blk * 32 + (w & 1) * 16 + lc;
    int b = pxg / HW_;
    int p = pxg - b * HW_;

    bf16x8 bH[4], bL[4];
    #pragma unroll
    for (int ks = 0; ks < 4; ++ks) {
        bH[ks] = *(const bf16x8*)&yHp[(size_t)pxg * HC_ + ks * 32 + grp * 8];
        bL[ks] = *(const bf16x8*)&yLp[(size_t)pxg * HC_ + ks * 32 + grp * 8];
    }

    int otBase = (w >> 1) * 4;
    #pragma unroll
    for (int oi = 0; oi < 4; ++oi) {
        int ot = otBase + oi;
        const unsigned short* wrH = WwH + (size_t)(ot * 16 + lc) * HC_ + grp * 8;
        const unsigned short* wrL = WwL + (size_t)(ot * 16 + lc) * HC_ + grp * 8;
        f32x4 acc = {0.f, 0.f, 0.f, 0.f};
        #pragma unroll
        for (int ks = 0; ks < 4; ++ks) {
            bf16x8 aH = *(const bf16x8*)(wrH + ks * 32);
            bf16x8 aL = *(const bf16x8*)(wrL + ks * 32);
            acc = __builtin_amdgcn_mfma_f32_16x16x32_bf16(aH, bH[ks], acc, 0, 0, 0);
            acc = __builtin_amdgcn_mfma_f32_16x16x32_bf16(aH, bL[ks], acc, 0, 0, 0);
            acc = __builtin_amdgcn_mfma_f32_16x16x32_bf16(aL, bH[ks], acc, 0, 0, 0);
        }
        int o0 = ot * 16 + grp * 4;
        #pragma unroll
        for (int r2 = 0; r2 < 4; ++r2)
            wyO[(size_t)(b * C_ + o0 + r2) * HW_ + p] = acc[r2];
    }
}

// ---------------------------------------------------------------------------
// 4) BN batch stats per channel -> folded scale/shift.  grid = 256
__global__ __launch_bounds__(256) void bn_stats_kernel(
    const float* __restrict__ wy, const float* __restrict__ gamma,
    const float* __restrict__ beta, float2* __restrict__ stats)
{
    int o = blockIdx.x;
    int tid = threadIdx.x;
    float s = 0.f, s2 = 0.f;
    for (int idx = tid; idx < NP_; idx += 256) {
        int b = idx / HW_;
        int p = idx - b * HW_;
        float v = wy[(size_t)(b * C_ + o) * HW_ + p];
        s += v;
        s2 = fmaf(v, v, s2);
    }
    #pragma unroll
    for (int off = 32; off; off >>= 1) {
        s  += __shfl_xor(s, off);
        s2 += __shfl_xor(s2, off);
    }
    __shared__ float ls[4], ls2[4];
    int wv = tid >> 6, lane = tid & 63;
    if (lane == 0) { ls[wv] = s; ls2[wv] = s2; }
    __syncthreads();
    if (tid == 0) {
        float S  = ls[0] + ls[1] + ls[2] + ls[3];
        float S2 = ls2[0] + ls2[1] + ls2[2] + ls2[3];
        float mean = S / (float)NP_;
        float var = fmaxf(S2 / (float)NP_ - mean * mean, 0.f);
        float rstd = rsqrtf(var + 1e-5f);
        float sc = gamma[o] * rstd;
        stats[o] = make_float2(sc, beta[o] - mean * sc);
    }
}

// ---------------------------------------------------------------------------
// 5) z = x + wy*scale + shift
__global__ __launch_bounds__(256) void final_kernel(
    const float* __restrict__ x, const float* __restrict__ wy,
    const float2* __restrict__ stats, float* __restrict__ out)
{
    int idx = blockIdx.x * 256 + threadIdx.x;
    int e0 = idx * 4;
    int c = (e0 / HW_) & (C_ - 1);
    float2 st = stats[c];
    float4 xv = *(const float4*)(x + e0);
    float4 wv = *(const float4*)(wy + e0);
    float4 o;
    o.x = fmaf(wv.x, st.x, xv.x + st.y);
    o.y = fmaf(wv.y, st.x, xv.y + st.y);
    o.z = fmaf(wv.z, st.x, xv.z + st.y);
    o.w = fmaf(wv.w, st.x, xv.w + st.y);
    *(float4*)(out + e0) = o;
}

extern "C" void kernel_launch(void* const* d_in, const int* in_sizes, int n_in,
                              void* d_out, int out_size, void* d_ws, size_t ws_size,
                              hipStream_t stream) {
    const float* x       = (const float*)d_in[0];
    const float* ctx     = (const float*)d_in[1];
    const float* theta_w = (const float*)d_in[2];
    const float* psi_w   = (const float*)d_in[3];
    const float* g_w     = (const float*)d_in[4];
    const float* W_w     = (const float*)d_in[5];
    // d_in[6] = W_b: unused, cancels exactly under training-mode BN
    const float* gamma   = (const float*)d_in[7];
    const float* beta    = (const float*)d_in[8];
    float* out = (float*)d_out;

    unsigned short* qH   = (unsigned short*)d_ws;   // [B,HW,128]        589824
    unsigned short* qL   = qH + 589824;
    unsigned short* psiH = qL + 589824;             // [B,3,HW,128]     1769472
    unsigned short* psiL = psiH + 1769472;
    unsigned short* gB   = psiL + 1769472;          // [B,128,3,48,64]  4718592
    unsigned short* yH   = gB + 4718592;            // [B,HW,128]        589824
    unsigned short* yL   = yH + 589824;
    unsigned short* WpgH = yL + 589824;             // [256,256]          65536
    unsigned short* WpgL = WpgH + 65536;
    unsigned short* WqH  = WpgL + 65536;            // [128,256]          32768
    unsigned short* WqL  = WqH + 32768;
    unsigned short* WwH  = WqL + 32768;             // [256,128]          32768
    unsigned short* WwL  = WwH + 32768;
    float* wyB = (float*)(WwL + 32768);             // [B,256,HW]       1179648
    float2* stats = (float2*)(wyB + 1179648);       // [256]

    split_w_kernel<<<dim3(128), 256, 0, stream>>>(psi_w, g_w, theta_w, W_w,
                                                  WpgH, WpgL, WqH, WqL, WwH, WwL);
    proj_mfma_kernel<<<dim3(576), 512, 0, stream>>>(WpgH, WpgL, WqH, WqL, ctx, x,
                                                    psiH, psiL, gB, qH, qL);
    pad_g_kernel<<<dim3(144), 256, 0, stream>>>(gB);
    attn_mfma_kernel<<<dim3(288), 512, 0, stream>>>(qH, qL, psiH, psiL, gB, yH, yL);
    wy_mfma_kernel<<<dim3(144), 512, 0, stream>>>(WwH, WwL, yH, yL, wyB);
    bn_stats_kernel<<<dim3(C_), 256, 0, stream>>>(wyB, gamma, beta, stats);
    final_kernel<<<dim3(B_ * C_ * HW_ / 4 / 256), 256, 0, stream>>>(x, wyB, stats, out);
}